// Round 5
// baseline (229.882 us; speedup 1.0000x reference)
//
#include <hip/hip_runtime.h>

#define K_SEGS 8192
#define ALPHA_W 0.5f
#define NEG_INF_BITS 0xFF800000

// ---------------------------------------------------------------------------
// Kernel 0: init workspace (ws is poisoned 0xAA before timing, never re-poisoned)
// ---------------------------------------------------------------------------
__global__ void init_ws_kernel(float* __restrict__ seg_sum,
                               int* __restrict__ seg_max_bits) {
    int k = blockIdx.x * blockDim.x + threadIdx.x;
    if (k < K_SEGS) {
        seg_sum[k] = 0.0f;
        seg_max_bits[k] = (int)NEG_INF_BITS;  // -inf; node_loss >= 0 so signed-int max ordering is valid
    }
}

// ---------------------------------------------------------------------------
// Kernel 1: per-node focal loss + segmented sum/max (sorted complex_id)
// ---------------------------------------------------------------------------
__global__ __launch_bounds__(256) void node_loss_kernel(
        const float* __restrict__ logits,   // [N, 8]
        const int* __restrict__ targets,    // [N]
        const int* __restrict__ cid,        // [N], sorted
        float* __restrict__ seg_sum,        // [K]
        int* __restrict__ seg_max_bits,     // [K]
        int n) {
    const int stride = gridDim.x * blockDim.x;
    const int lane = threadIdx.x & 63;

    int i = blockIdx.x * blockDim.x + threadIdx.x;
    // __any keeps the whole wave in the loop together (needed for shfl reduce)
    while (__any(i < n)) {
        bool valid = (i < n);
        float loss = 0.0f;
        int id = -1;
        if (valid) {
            // 8 logits = 32 B contiguous: two float4 loads
            const float4* lg = reinterpret_cast<const float4*>(logits) + (size_t)i * 2;
            float4 a = lg[0];
            float4 b = lg[1];
            float x0 = a.x, x1 = a.y, x2 = a.z, x3 = a.w;
            float x4 = b.x, x5 = b.y, x6 = b.z, x7 = b.w;

            float m = fmaxf(fmaxf(fmaxf(x0, x1), fmaxf(x2, x3)),
                            fmaxf(fmaxf(x4, x5), fmaxf(x6, x7)));
            float s = __expf(x0 - m) + __expf(x1 - m) + __expf(x2 - m) + __expf(x3 - m)
                    + __expf(x4 - m) + __expf(x5 - m) + __expf(x6 - m) + __expf(x7 - m);
            float lse = __logf(s) + m;

            int t = targets[i];
            float xt;
            switch (t) {
                case 0: xt = x0; break; case 1: xt = x1; break;
                case 2: xt = x2; break; case 3: xt = x3; break;
                case 4: xt = x4; break; case 5: xt = x5; break;
                case 6: xt = x6; break; default: xt = x7; break;
            }
            float ce = lse - xt;              // >= 0
            float pt = __expf(-ce);           // in (0, 1]
            float om = 1.0f - pt;
            loss = om * om * ce;              // >= 0
            id = cid[i];
        }

        int id0 = __shfl(id, 0);
        bool uniform = __all(id == id0);
        if (uniform) {
            // whole wave in one segment (implies all lanes valid): 1 atomic pair/wave
            float ssum = loss, smax = loss;
            #pragma unroll
            for (int off = 32; off > 0; off >>= 1) {
                ssum += __shfl_xor(ssum, off);
                smax = fmaxf(smax, __shfl_xor(smax, off));
            }
            if (lane == 0) {
                atomicAdd(&seg_sum[id0], ssum);
                atomicMax(&seg_max_bits[id0], __float_as_int(smax));
            }
        } else if (valid) {
            // boundary wave (~13% of waves): per-lane atomics
            atomicAdd(&seg_sum[id], loss);
            atomicMax(&seg_max_bits[id], __float_as_int(loss));
        }

        i += stride;
    }
}

// ---------------------------------------------------------------------------
// Kernel 2: reduce K segments -> scalar
// ---------------------------------------------------------------------------
__global__ __launch_bounds__(256) void finalize_kernel(
        const float* __restrict__ seg_sum,
        const int* __restrict__ seg_max_bits,
        float* __restrict__ out) {
    __shared__ float s_acc[4];
    __shared__ float s_cnt[4];

    float acc = 0.0f, cnt = 0.0f;
    for (int k = threadIdx.x; k < K_SEGS; k += blockDim.x) {
        int mb = seg_max_bits[k];
        if (mb != (int)NEG_INF_BITS) {   // present (>= 1 node wrote a max >= 0)
            float mx = __int_as_float(mb);
            acc += ALPHA_W * seg_sum[k] + (1.0f - ALPHA_W) * mx;
            cnt += 1.0f;
        }
    }
    #pragma unroll
    for (int off = 32; off > 0; off >>= 1) {
        acc += __shfl_xor(acc, off);
        cnt += __shfl_xor(cnt, off);
    }
    int wid = threadIdx.x >> 6;
    if ((threadIdx.x & 63) == 0) { s_acc[wid] = acc; s_cnt[wid] = cnt; }
    __syncthreads();
    if (threadIdx.x == 0) {
        float a = s_acc[0] + s_acc[1] + s_acc[2] + s_acc[3];
        float c = s_cnt[0] + s_cnt[1] + s_cnt[2] + s_cnt[3];
        out[0] = a / fmaxf(c, 1.0f);
    }
}

// ---------------------------------------------------------------------------
extern "C" void kernel_launch(void* const* d_in, const int* in_sizes, int n_in,
                              void* d_out, int out_size, void* d_ws, size_t ws_size,
                              hipStream_t stream) {
    const float* logits = (const float*)d_in[0];
    const int* targets  = (const int*)d_in[1];
    const int* cid      = (const int*)d_in[2];
    float* out          = (float*)d_out;

    const int n = in_sizes[1];   // N = 4,000,000 (targets element count)

    float* seg_sum     = (float*)d_ws;
    int* seg_max_bits  = (int*)((char*)d_ws + K_SEGS * sizeof(float));

    init_ws_kernel<<<K_SEGS / 256, 256, 0, stream>>>(seg_sum, seg_max_bits);

    const int block = 256;
    const int grid = 2048;   // ~8 blocks/CU worth of waves; grid-stride covers N
    node_loss_kernel<<<grid, block, 0, stream>>>(logits, targets, cid,
                                                 seg_sum, seg_max_bits, n);

    finalize_kernel<<<1, 256, 0, stream>>>(seg_sum, seg_max_bits, out);
}

// Round 6
// 54.212 us; speedup vs baseline: 4.2404x; 4.2404x over previous
//
#include <hip/hip_runtime.h>

#define K_SEGS 8192
#define ALPHA_W 0.5f
#define NEG_INF_BITS 0xFF800000
#define LDS_CAP 1024          // segment-id window per block (chunk spans ~8 ids; 1024 = huge margin)
#define NBLOCKS 2048
#define BLOCK 256

// ---------------------------------------------------------------------------
// Kernel 0: init global accumulators (ws poisoned 0xAA once, never re-poisoned)
// ---------------------------------------------------------------------------
__global__ void init_ws_kernel(float* __restrict__ seg_sum,
                               int* __restrict__ seg_max_bits) {
    int k = blockIdx.x * blockDim.x + threadIdx.x;
    if (k < K_SEGS) {
        seg_sum[k] = 0.0f;
        seg_max_bits[k] = (int)NEG_INF_BITS;  // node_loss >= 0 so signed-int max ordering valid
    }
}

// ---------------------------------------------------------------------------
// Kernel 1: focal loss + LDS-privatized segmented sum/max (sorted complex_id)
// Each block owns a CONTIGUOUS node chunk -> touches a narrow id window.
// ---------------------------------------------------------------------------
__global__ __launch_bounds__(BLOCK) void node_loss_kernel(
        const float* __restrict__ logits,   // [N, 8]
        const int* __restrict__ targets,    // [N]
        const int* __restrict__ cid,        // [N], sorted
        float* __restrict__ seg_sum,        // [K]
        int* __restrict__ seg_max_bits,     // [K]
        int n) {
    __shared__ float lsum[LDS_CAP];
    __shared__ int   lmax[LDS_CAP];

    const int tid  = threadIdx.x;
    const int lane = tid & 63;

    const int chunk  = (n + NBLOCKS - 1) / NBLOCKS;
    const int cstart = blockIdx.x * chunk;
    if (cstart >= n) return;                 // whole block exits together
    const int cend = min(cstart + chunk, n);
    const int base = cid[cstart];            // same addr all threads -> broadcast load

    for (int j = tid; j < LDS_CAP; j += BLOCK) {
        lsum[j] = 0.0f;
        lmax[j] = (int)NEG_INF_BITS;
    }
    __syncthreads();

    // lanes are consecutive i -> valid lanes form a prefix; lane 0 valid iff any valid
    for (int i = cstart + tid; __any(i < cend); i += BLOCK) {
        bool valid = (i < cend);
        float loss = 0.0f;
        int off = -1;
        if (valid) {
            const float4* lg = reinterpret_cast<const float4*>(logits) + (size_t)i * 2;
            float4 a = lg[0];
            float4 b = lg[1];
            float x0 = a.x, x1 = a.y, x2 = a.z, x3 = a.w;
            float x4 = b.x, x5 = b.y, x6 = b.z, x7 = b.w;

            float m = fmaxf(fmaxf(fmaxf(x0, x1), fmaxf(x2, x3)),
                            fmaxf(fmaxf(x4, x5), fmaxf(x6, x7)));
            float s = __expf(x0 - m) + __expf(x1 - m) + __expf(x2 - m) + __expf(x3 - m)
                    + __expf(x4 - m) + __expf(x5 - m) + __expf(x6 - m) + __expf(x7 - m);
            float lse = __logf(s) + m;

            int t = targets[i];
            float xt;
            switch (t) {
                case 0: xt = x0; break; case 1: xt = x1; break;
                case 2: xt = x2; break; case 3: xt = x3; break;
                case 4: xt = x4; break; case 5: xt = x5; break;
                case 6: xt = x6; break; default: xt = x7; break;
            }
            float ce = lse - xt;              // >= 0
            float pt = __expf(-ce);           // (0, 1]
            float om = 1.0f - pt;
            loss = om * om * ce;              // >= 0
            off = cid[i] - base;              // >= 0 by sortedness
        }

        int off0 = __shfl(off, 0);
        bool uniform = __all(off == off0) && (off0 < LDS_CAP);
        if (uniform) {
            // whole wave, one segment (all lanes valid since off==-1 would differ)
            float ssum = loss, smax = loss;
            #pragma unroll
            for (int o = 32; o > 0; o >>= 1) {
                ssum += __shfl_xor(ssum, o);
                smax = fmaxf(smax, __shfl_xor(smax, o));
            }
            if (lane == 0) {
                atomicAdd(&lsum[off0], ssum);
                atomicMax(&lmax[off0], __float_as_int(smax));
            }
        } else if (valid) {
            if (off < LDS_CAP) {
                atomicAdd(&lsum[off], loss);
                atomicMax(&lmax[off], __float_as_int(loss));
            } else {
                // id window overflow (pathological data) — correctness fallback
                atomicAdd(&seg_sum[base + off], loss);
                atomicMax(&seg_max_bits[base + off], __float_as_int(loss));
            }
        }
    }
    __syncthreads();

    // flush touched window entries: ~8-16 global atomic pairs per block
    for (int j = tid; j < LDS_CAP; j += BLOCK) {
        int mb = lmax[j];
        if (mb != (int)NEG_INF_BITS) {
            atomicAdd(&seg_sum[base + j], lsum[j]);
            atomicMax(&seg_max_bits[base + j], mb);
        }
    }
}

// ---------------------------------------------------------------------------
// Kernel 2: reduce K segments -> scalar
// ---------------------------------------------------------------------------
__global__ __launch_bounds__(256) void finalize_kernel(
        const float* __restrict__ seg_sum,
        const int* __restrict__ seg_max_bits,
        float* __restrict__ out) {
    __shared__ float s_acc[4];
    __shared__ float s_cnt[4];

    float acc = 0.0f, cnt = 0.0f;
    for (int k = threadIdx.x; k < K_SEGS; k += blockDim.x) {
        int mb = seg_max_bits[k];
        if (mb != (int)NEG_INF_BITS) {
            float mx = __int_as_float(mb);
            acc += ALPHA_W * seg_sum[k] + (1.0f - ALPHA_W) * mx;
            cnt += 1.0f;
        }
    }
    #pragma unroll
    for (int o = 32; o > 0; o >>= 1) {
        acc += __shfl_xor(acc, o);
        cnt += __shfl_xor(cnt, o);
    }
    int wid = threadIdx.x >> 6;
    if ((threadIdx.x & 63) == 0) { s_acc[wid] = acc; s_cnt[wid] = cnt; }
    __syncthreads();
    if (threadIdx.x == 0) {
        float a = s_acc[0] + s_acc[1] + s_acc[2] + s_acc[3];
        float c = s_cnt[0] + s_cnt[1] + s_cnt[2] + s_cnt[3];
        out[0] = a / fmaxf(c, 1.0f);
    }
}

// ---------------------------------------------------------------------------
extern "C" void kernel_launch(void* const* d_in, const int* in_sizes, int n_in,
                              void* d_out, int out_size, void* d_ws, size_t ws_size,
                              hipStream_t stream) {
    const float* logits = (const float*)d_in[0];
    const int* targets  = (const int*)d_in[1];
    const int* cid      = (const int*)d_in[2];
    float* out          = (float*)d_out;

    const int n = in_sizes[1];   // N = 4,000,000

    float* seg_sum    = (float*)d_ws;
    int* seg_max_bits = (int*)((char*)d_ws + K_SEGS * sizeof(float));

    init_ws_kernel<<<K_SEGS / 256, 256, 0, stream>>>(seg_sum, seg_max_bits);

    node_loss_kernel<<<NBLOCKS, BLOCK, 0, stream>>>(logits, targets, cid,
                                                    seg_sum, seg_max_bits, n);

    finalize_kernel<<<1, 256, 0, stream>>>(seg_sum, seg_max_bits, out);
}